// Round 1
// baseline (1680.348 us; speedup 1.0000x reference)
//
#include <hip/hip_runtime.h>

// NeuronGAT forward: 3x(GAT + BN + residual + leaky) -> JK-max -> 2-head full
// self-attention over 8192 nodes -> MLP head. All fp32.
// Round 0: correctness-first baseline. Atomics used for segment ops (tiny
// reorder noise ~1e-7, well under threshold).

#define NEG 0.2f

__device__ __forceinline__ float leaky(float v) { return v > 0.f ? v : NEG * v; }

// monotonic float<->uint mapping for atomicMax on floats
__device__ __forceinline__ unsigned fmap(float f) {
    unsigned u = __float_as_uint(f);
    return (u & 0x80000000u) ? ~u : (u | 0x80000000u);
}
__device__ __forceinline__ float funmap(unsigned u) {
    unsigned b = (u & 0x80000000u) ? (u & 0x7FFFFFFFu) : ~u;
    return __uint_as_float(b);
}

// ---------------------------------------------------------------- GEMM
// C[M,N] = act(A[M,K] @ B[K,N] + bias). M % 64 == 0, K % 16 == 0, N arbitrary.
// 64x64 tile, 256 threads, 4x4 microtile.
__global__ __launch_bounds__(256) void gemm_bias_act(
    const float* __restrict__ A, const float* __restrict__ B,
    const float* __restrict__ bias, float* __restrict__ C,
    int M, int N, int K, int act)
{
    __shared__ __align__(16) float As[16][68];
    __shared__ __align__(16) float Bs[16][68];
    const int tx = threadIdx.x & 15, ty = threadIdx.x >> 4;
    const int row0 = blockIdx.y * 64 + ty * 4;
    const int col0 = blockIdx.x * 64 + tx * 4;
    float acc[4][4] = {};
    for (int k0 = 0; k0 < K; k0 += 16) {
        for (int idx = threadIdx.x; idx < 64 * 16; idx += 256) {
            int r = idx >> 4, kk = idx & 15;
            As[kk][r] = A[(size_t)(blockIdx.y * 64 + r) * K + k0 + kk];
        }
        for (int idx = threadIdx.x; idx < 16 * 64; idx += 256) {
            int kk = idx >> 6, cc = idx & 63;
            int col = blockIdx.x * 64 + cc;
            Bs[kk][cc] = (col < N) ? B[(size_t)(k0 + kk) * N + col] : 0.f;
        }
        __syncthreads();
#pragma unroll
        for (int kk = 0; kk < 16; ++kk) {
            float4 a4 = *(const float4*)&As[kk][ty * 4];
            float4 b4 = *(const float4*)&Bs[kk][tx * 4];
            float a[4] = {a4.x, a4.y, a4.z, a4.w};
            float b[4] = {b4.x, b4.y, b4.z, b4.w};
#pragma unroll
            for (int i = 0; i < 4; ++i)
#pragma unroll
                for (int j = 0; j < 4; ++j) acc[i][j] += a[i] * b[j];
        }
        __syncthreads();
    }
#pragma unroll
    for (int i = 0; i < 4; ++i) {
        int r = row0 + i;
#pragma unroll
        for (int j = 0; j < 4; ++j) {
            int c = col0 + j;
            if (c < N) {
                float v = acc[i][j] + (bias ? bias[c] : 0.f);
                if (act) v = leaky(v);
                C[(size_t)r * N + c] = v;
            }
        }
    }
}

// ------------------------------------------------- GAT attention scores
// s[n,h] = dot(hw[n,h,:], a_s[h,:]) ; d likewise
__global__ void sd_kernel(const float* __restrict__ hw, const float* __restrict__ a_s,
                          const float* __restrict__ a_d, float* __restrict__ sval,
                          float* __restrict__ dval, int Nn, int H)
{
    int i = blockIdx.x * blockDim.x + threadIdx.x;
    if (i >= Nn * H) return;
    int n = i / H, h = i - n * H;
    const float4* row = (const float4*)(hw + (size_t)n * H * 64 + h * 64);
    const float4* as4 = (const float4*)(a_s + h * 64);
    const float4* ad4 = (const float4*)(a_d + h * 64);
    float s = 0.f, d = 0.f;
#pragma unroll
    for (int c = 0; c < 16; ++c) {
        float4 x = row[c], a = as4[c], b = ad4[c];
        s += x.x * a.x + x.y * a.y + x.z * a.z + x.w * a.w;
        d += x.x * b.x + x.y * b.y + x.z * b.z + x.w * b.w;
    }
    sval[i] = s;
    dval[i] = d;
}

__global__ void edge_score(const int* __restrict__ ei, const float* __restrict__ sval,
                           const float* __restrict__ dval, float* __restrict__ ee,
                           unsigned* __restrict__ mmax, int E, int Etot, int H)
{
    int i = blockIdx.x * blockDim.x + threadIdx.x;
    if (i >= Etot * H) return;
    int e = i / H, h = i - e * H;
    int s, d;
    if (e < E) { s = ei[e]; d = ei[E + e]; } else { s = d = e - E; }
    float v = leaky(sval[s * H + h] + dval[d * H + h]);
    ee[i] = v;
    atomicMax(&mmax[d * H + h], fmap(v));
}

__global__ void edge_expsum(const int* __restrict__ ei, float* __restrict__ ee,
                            const unsigned* __restrict__ mmax, float* __restrict__ den,
                            int E, int Etot, int H)
{
    int i = blockIdx.x * blockDim.x + threadIdx.x;
    if (i >= Etot * H) return;
    int e = i / H, h = i - e * H;
    int d;
    if (e < E) { d = ei[E + e]; } else { d = e - E; }
    float m = funmap(mmax[d * H + h]);
    float ex = __expf(ee[i] - m);
    ee[i] = ex;
    atomicAdd(&den[d * H + h], ex);
}

// one wave per edge; 64 lanes cover the 64 channels of each head
__global__ __launch_bounds__(256) void edge_accum(
    const int* __restrict__ ei, const float* __restrict__ hw,
    const float* __restrict__ ee, const float* __restrict__ den,
    float* __restrict__ gout, int E, int Etot, int H)
{
    int edge = blockIdx.x * 4 + (threadIdx.x >> 6);
    int lane = threadIdx.x & 63;
    if (edge >= Etot) return;
    int s, d;
    if (edge < E) { s = ei[edge]; d = ei[E + edge]; } else { s = d = edge - E; }
    int C = H * 64;
    for (int h = 0; h < H; ++h) {
        float alpha = ee[(size_t)edge * H + h] / (den[d * H + h] + 1e-16f);
        atomicAdd(&gout[(size_t)d * C + h * 64 + lane],
                  hw[(size_t)s * C + h * 64 + lane] * alpha);
    }
}

// ------------------------------------------------- BatchNorm (batch stats)
__global__ void bn_partial(const float* __restrict__ gout, double* __restrict__ sums,
                           int Nn, int C)
{
    int t = threadIdx.x;
    int c = t % C, sub = t / C, nsub = blockDim.x / C;
    int rbase = blockIdx.x * 32;
    double s = 0.0, sq = 0.0;
    for (int r = rbase + sub; r < rbase + 32; r += nsub) {
        float x = gout[(size_t)r * C + c];
        s += x;
        sq += (double)x * x;
    }
    atomicAdd(&sums[c], s);
    atomicAdd(&sums[C + c], sq);
}

__global__ void bn_finalize(const double* __restrict__ sums, float* __restrict__ mu,
                            float* __restrict__ rstd, int Nn, int C)
{
    int c = threadIdx.x;
    if (c >= C) return;
    double m = sums[c] / Nn;
    double v = sums[C + c] / Nn - m * m;
    mu[c] = (float)m;
    rstd[c] = (float)(1.0 / sqrt(v + 1e-5));
}

__global__ void bn_res_act(const float* __restrict__ gout, const float* __restrict__ res,
                           const float* __restrict__ mu, const float* __restrict__ rstd,
                           const float* __restrict__ g, const float* __restrict__ be,
                           float* __restrict__ out, int total, int C)
{
    int i = blockIdx.x * blockDim.x + threadIdx.x;
    if (i >= total) return;
    int c = i & (C - 1);
    float v = (gout[i] - mu[c]) * rstd[c] * g[c] + be[c] + res[i];
    out[i] = leaky(v);
}

__global__ void jk_max(const float* __restrict__ a, const float* __restrict__ b,
                       const float* __restrict__ c, float* __restrict__ z, int total)
{
    int i = blockIdx.x * blockDim.x + threadIdx.x;
    if (i >= total) return;
    z[i] = fmaxf(fmaxf(a[i], b[i]), c[i]);
}

// ------------------------------------------------- full self-attention
// grid (N/8, heads). 4 waves/block; each wave owns 2 q-rows; lanes split keys.
// K/V tiles (128x32) staged in LDS as float4 with XOR swizzle (conflict-min).
__global__ __launch_bounds__(256) void attn_kernel(
    const float* __restrict__ qg, const float* __restrict__ kg,
    const float* __restrict__ vg, float* __restrict__ og, int N)
{
    __shared__ float4 klds[128 * 8];
    __shared__ float4 vlds[128 * 8];
    const int head = blockIdx.y;
    const int wid = threadIdx.x >> 6, lane = threadIdx.x & 63;
    const int q0row = (blockIdx.x * 4 + wid) * 2;
    const float scale = 0.17677669529663687f; // 1/sqrt(32)

    float qv0[32], qv1[32];
#pragma unroll
    for (int c = 0; c < 32; ++c) {
        qv0[c] = qg[(size_t)q0row * 64 + head * 32 + c];
        qv1[c] = qg[(size_t)(q0row + 1) * 64 + head * 32 + c];
    }
    float m0 = -1e30f, m1 = -1e30f, l0 = 0.f, l1 = 0.f;
    float acc0[32] = {}, acc1[32] = {};

    for (int t0 = 0; t0 < N; t0 += 128) {
        __syncthreads();
        for (int idx = threadIdx.x; idx < 128 * 8; idx += 256) {
            int r = idx >> 3, c4 = idx & 7;
            int sw = r * 8 + (c4 ^ (r & 7));
            klds[sw] = *(const float4*)&kg[(size_t)(t0 + r) * 64 + head * 32 + c4 * 4];
            vlds[sw] = *(const float4*)&vg[(size_t)(t0 + r) * 64 + head * 32 + c4 * 4];
        }
        __syncthreads();
#pragma unroll
        for (int kk = 0; kk < 2; ++kk) {
            const int key = lane + kk * 64;
            float s0 = 0.f, s1 = 0.f;
#pragma unroll
            for (int c4 = 0; c4 < 8; ++c4) {
                float4 k4 = klds[key * 8 + (c4 ^ (key & 7))];
                s0 += qv0[c4 * 4] * k4.x + qv0[c4 * 4 + 1] * k4.y +
                      qv0[c4 * 4 + 2] * k4.z + qv0[c4 * 4 + 3] * k4.w;
                s1 += qv1[c4 * 4] * k4.x + qv1[c4 * 4 + 1] * k4.y +
                      qv1[c4 * 4 + 2] * k4.z + qv1[c4 * 4 + 3] * k4.w;
            }
            s0 *= scale;
            s1 *= scale;
            if (s0 > m0) {
                float corr = __expf(m0 - s0);
                l0 *= corr;
#pragma unroll
                for (int c = 0; c < 32; ++c) acc0[c] *= corr;
                m0 = s0;
            }
            float p0 = __expf(s0 - m0);
            l0 += p0;
            if (s1 > m1) {
                float corr = __expf(m1 - s1);
                l1 *= corr;
#pragma unroll
                for (int c = 0; c < 32; ++c) acc1[c] *= corr;
                m1 = s1;
            }
            float p1 = __expf(s1 - m1);
            l1 += p1;
#pragma unroll
            for (int c4 = 0; c4 < 8; ++c4) {
                float4 v4 = vlds[key * 8 + (c4 ^ (key & 7))];
                acc0[c4 * 4] += p0 * v4.x;
                acc0[c4 * 4 + 1] += p0 * v4.y;
                acc0[c4 * 4 + 2] += p0 * v4.z;
                acc0[c4 * 4 + 3] += p0 * v4.w;
                acc1[c4 * 4] += p1 * v4.x;
                acc1[c4 * 4 + 1] += p1 * v4.y;
                acc1[c4 * 4 + 2] += p1 * v4.z;
                acc1[c4 * 4 + 3] += p1 * v4.w;
            }
        }
    }
    // merge (m,l,acc) across the 64 lanes, online-softmax style butterfly
#pragma unroll
    for (int off = 1; off < 64; off <<= 1) {
        {
            float m2 = __shfl_xor(m0, off), l2 = __shfl_xor(l0, off);
            float nm = fmaxf(m0, m2);
            float c1 = __expf(m0 - nm), c2 = __expf(m2 - nm);
            l0 = l0 * c1 + l2 * c2;
#pragma unroll
            for (int c = 0; c < 32; ++c) {
                float a2 = __shfl_xor(acc0[c], off);
                acc0[c] = acc0[c] * c1 + a2 * c2;
            }
            m0 = nm;
        }
        {
            float m2 = __shfl_xor(m1, off), l2 = __shfl_xor(l1, off);
            float nm = fmaxf(m1, m2);
            float c1 = __expf(m1 - nm), c2 = __expf(m2 - nm);
            l1 = l1 * c1 + l2 * c2;
#pragma unroll
            for (int c = 0; c < 32; ++c) {
                float a2 = __shfl_xor(acc1[c], off);
                acc1[c] = acc1[c] * c1 + a2 * c2;
            }
            m1 = nm;
        }
    }
    if (lane == 0) {
        float i0 = 1.f / l0, i1 = 1.f / l1;
        for (int c = 0; c < 32; ++c) {
            og[(size_t)q0row * 64 + head * 32 + c] = acc0[c] * i0;
            og[(size_t)(q0row + 1) * 64 + head * 32 + c] = acc1[c] * i1;
        }
    }
}

// ----------------------------------------------------------------- host
extern "C" void kernel_launch(void* const* d_in, const int* in_sizes, int n_in,
                              void* d_out, int out_size, void* d_ws, size_t ws_size,
                              hipStream_t stream)
{
    const float* x = (const float*)d_in[0];
    const int* ei = (const int*)d_in[1];
    const float* w[3]  = {(const float*)d_in[2], (const float*)d_in[6],  (const float*)d_in[10]};
    const float* as_[3] = {(const float*)d_in[3], (const float*)d_in[7],  (const float*)d_in[11]};
    const float* ad_[3] = {(const float*)d_in[4], (const float*)d_in[8],  (const float*)d_in[12]};
    const float* rw[3] = {(const float*)d_in[5], (const float*)d_in[9],  (const float*)d_in[13]};
    const float* p0 = (const float*)d_in[14];
    const float* p1 = (const float*)d_in[15];
    const float* qw = (const float*)d_in[16];
    const float* kw = (const float*)d_in[17];
    const float* vw = (const float*)d_in[18];
    const float* ow = (const float*)d_in[19];
    const float* m1w = (const float*)d_in[20];
    const float* m2w = (const float*)d_in[21];
    const float* m3w = (const float*)d_in[22];
    const float* g_[3]  = {(const float*)d_in[23], (const float*)d_in[24], (const float*)d_in[25]};
    const float* be_[3] = {(const float*)d_in[26], (const float*)d_in[27], (const float*)d_in[28]};
    // d_in[29..31] = b0,b1,b2: constant shift cancels exactly inside BatchNorm -> unused
    const float* qb  = (const float*)d_in[32];
    const float* kb  = (const float*)d_in[33];
    const float* vb  = (const float*)d_in[34];
    const float* ob  = (const float*)d_in[35];
    const float* m1b = (const float*)d_in[36];
    const float* m2b = (const float*)d_in[37];
    const float* m3b = (const float*)d_in[38];

    const int N = in_sizes[0] / 64;     // 8192
    const int E = in_sizes[1] / 2;      // 262144
    const int Etot = E + N;             // with self-loops

    float* ws = (float*)d_ws;
    size_t off = 0;
    auto alloc = [&](size_t n) {
        float* p = ws + off;
        off += (n + 255) & ~(size_t)255;
        return p;
    };
    float* hw   = alloc((size_t)N * 256);
    float* res  = alloc((size_t)N * 256);
    float* gout = alloc((size_t)N * 256);
    float* h0   = alloc((size_t)N * 256);
    float* h1   = alloc((size_t)N * 256);
    float* h2   = alloc((size_t)N * 64);
    float* sval = alloc((size_t)N * 4);
    float* dval = alloc((size_t)N * 4);
    float* mmax = alloc((size_t)N * 4);
    float* den  = alloc((size_t)N * 4);
    float* ee   = alloc((size_t)Etot * 4);
    double* bnsum = (double*)alloc(1024);   // 2*256 doubles
    float* mu   = alloc(256);
    float* rstd = alloc(256);
    // aliases for the post-GAT stages (hw/res/gout free by then)
    float* zq = hw;
    float* zk = hw + (size_t)N * 64;
    float* zv = hw + 2 * (size_t)N * 64;
    float* ao = hw + 3 * (size_t)N * 64;
    float* z  = gout;
    float* tA = res;
    float* tB = res + (size_t)N * 64;
    float* tC = res + 2 * (size_t)N * 64;

    auto gemm = [&](const float* A, const float* B, const float* bias, float* C,
                    int M, int Nc, int K, int act) {
        dim3 grid((Nc + 63) / 64, (M + 63) / 64);
        gemm_bias_act<<<grid, 256, 0, stream>>>(A, B, bias, C, M, Nc, K, act);
    };

    const float* hin = x;
    int Kin = 64;
    float* houts[3] = {h0, h1, h2};
    int heads[3] = {4, 4, 1};

    for (int l = 0; l < 3; ++l) {
        int H = heads[l], C = H * 64;
        gemm(hin, w[l], nullptr, hw, N, C, Kin, 0);
        gemm(hin, rw[l], nullptr, res, N, C, Kin, 0);
        sd_kernel<<<(N * H + 255) / 256, 256, 0, stream>>>(hw, as_[l], ad_[l], sval, dval, N, H);
        hipMemsetAsync(mmax, 0, (size_t)N * H * 4, stream);
        hipMemsetAsync(den, 0, (size_t)N * H * 4, stream);
        hipMemsetAsync(gout, 0, (size_t)N * C * 4, stream);
        int tot = Etot * H;
        edge_score<<<(tot + 255) / 256, 256, 0, stream>>>(ei, sval, dval, ee, (unsigned*)mmax, E, Etot, H);
        edge_expsum<<<(tot + 255) / 256, 256, 0, stream>>>(ei, ee, (const unsigned*)mmax, den, E, Etot, H);
        edge_accum<<<(Etot + 3) / 4, 256, 0, stream>>>(ei, hw, ee, den, gout, E, Etot, H);
        hipMemsetAsync(bnsum, 0, (size_t)2 * C * 8, stream);
        bn_partial<<<N / 32, 256, 0, stream>>>(gout, bnsum, N, C);
        bn_finalize<<<1, 256, 0, stream>>>(bnsum, mu, rstd, N, C);
        bn_res_act<<<((size_t)N * C) / 256, 256, 0, stream>>>(gout, res, mu, rstd, g_[l], be_[l], houts[l], N * C, C);
        hin = houts[l];
        Kin = C;
    }

    // JumpingKnowledge max
    gemm(h0, p0, nullptr, tA, N, 64, 256, 0);
    gemm(h1, p1, nullptr, tB, N, 64, 256, 0);
    jk_max<<<((size_t)N * 64) / 256, 256, 0, stream>>>(tA, tB, h2, z, N * 64);

    // self-attention
    gemm(z, qw, qb, zq, N, 64, 64, 0);
    gemm(z, kw, kb, zk, N, 64, 64, 0);
    gemm(z, vw, vb, zv, N, 64, 64, 0);
    attn_kernel<<<dim3(N / 8, 2), 256, 0, stream>>>(zq, zk, zv, ao, N);
    gemm(ao, ow, ob, tA, N, 64, 64, 0);

    // MLP head
    gemm(tA, m1w, m1b, tB, N, 64, 64, 1);
    gemm(tB, m2w, m2b, tC, N, 32, 64, 1);
    gemm(tC, m3w, m3b, (float*)d_out, N, 10, 32, 0);
}

// Round 2
// 1524.298 us; speedup vs baseline: 1.1024x; 1.1024x over previous
//
#include <hip/hip_runtime.h>

// NeuronGAT forward: 3x(GAT + BN + residual + leaky) -> JK-max -> 2-head full
// self-attention over 8192 nodes -> MLP head. All fp32.
// Round 1: attn rewritten as row-per-thread flash with key-chunk partials.
//   - broadcast LDS reads (no bank conflicts), no butterfly merge,
//     branchless sub-tile rescale. 8 key-chunks x 512 blocks + combine pass.

#define NEG 0.2f

__device__ __forceinline__ float leaky(float v) { return v > 0.f ? v : NEG * v; }

// monotonic float<->uint mapping for atomicMax on floats
__device__ __forceinline__ unsigned fmap(float f) {
    unsigned u = __float_as_uint(f);
    return (u & 0x80000000u) ? ~u : (u | 0x80000000u);
}
__device__ __forceinline__ float funmap(unsigned u) {
    unsigned b = (u & 0x80000000u) ? (u & 0x7FFFFFFFu) : ~u;
    return __uint_as_float(b);
}

// ---------------------------------------------------------------- GEMM
// C[M,N] = act(A[M,K] @ B[K,N] + bias). M % 64 == 0, K % 16 == 0, N arbitrary.
// 64x64 tile, 256 threads, 4x4 microtile.
__global__ __launch_bounds__(256) void gemm_bias_act(
    const float* __restrict__ A, const float* __restrict__ B,
    const float* __restrict__ bias, float* __restrict__ C,
    int M, int N, int K, int act)
{
    __shared__ __align__(16) float As[16][68];
    __shared__ __align__(16) float Bs[16][68];
    const int tx = threadIdx.x & 15, ty = threadIdx.x >> 4;
    const int row0 = blockIdx.y * 64 + ty * 4;
    const int col0 = blockIdx.x * 64 + tx * 4;
    float acc[4][4] = {};
    for (int k0 = 0; k0 < K; k0 += 16) {
        for (int idx = threadIdx.x; idx < 64 * 16; idx += 256) {
            int r = idx >> 4, kk = idx & 15;
            As[kk][r] = A[(size_t)(blockIdx.y * 64 + r) * K + k0 + kk];
        }
        for (int idx = threadIdx.x; idx < 16 * 64; idx += 256) {
            int kk = idx >> 6, cc = idx & 63;
            int col = blockIdx.x * 64 + cc;
            Bs[kk][cc] = (col < N) ? B[(size_t)(k0 + kk) * N + col] : 0.f;
        }
        __syncthreads();
#pragma unroll
        for (int kk = 0; kk < 16; ++kk) {
            float4 a4 = *(const float4*)&As[kk][ty * 4];
            float4 b4 = *(const float4*)&Bs[kk][tx * 4];
            float a[4] = {a4.x, a4.y, a4.z, a4.w};
            float b[4] = {b4.x, b4.y, b4.z, b4.w};
#pragma unroll
            for (int i = 0; i < 4; ++i)
#pragma unroll
                for (int j = 0; j < 4; ++j) acc[i][j] += a[i] * b[j];
        }
        __syncthreads();
    }
#pragma unroll
    for (int i = 0; i < 4; ++i) {
        int r = row0 + i;
#pragma unroll
        for (int j = 0; j < 4; ++j) {
            int c = col0 + j;
            if (c < N) {
                float v = acc[i][j] + (bias ? bias[c] : 0.f);
                if (act) v = leaky(v);
                C[(size_t)r * N + c] = v;
            }
        }
    }
}

// ------------------------------------------------- GAT attention scores
__global__ void sd_kernel(const float* __restrict__ hw, const float* __restrict__ a_s,
                          const float* __restrict__ a_d, float* __restrict__ sval,
                          float* __restrict__ dval, int Nn, int H)
{
    int i = blockIdx.x * blockDim.x + threadIdx.x;
    if (i >= Nn * H) return;
    int n = i / H, h = i - n * H;
    const float4* row = (const float4*)(hw + (size_t)n * H * 64 + h * 64);
    const float4* as4 = (const float4*)(a_s + h * 64);
    const float4* ad4 = (const float4*)(a_d + h * 64);
    float s = 0.f, d = 0.f;
#pragma unroll
    for (int c = 0; c < 16; ++c) {
        float4 x = row[c], a = as4[c], b = ad4[c];
        s += x.x * a.x + x.y * a.y + x.z * a.z + x.w * a.w;
        d += x.x * b.x + x.y * b.y + x.z * b.z + x.w * b.w;
    }
    sval[i] = s;
    dval[i] = d;
}

__global__ void edge_score(const int* __restrict__ ei, const float* __restrict__ sval,
                           const float* __restrict__ dval, float* __restrict__ ee,
                           unsigned* __restrict__ mmax, int E, int Etot, int H)
{
    int i = blockIdx.x * blockDim.x + threadIdx.x;
    if (i >= Etot * H) return;
    int e = i / H, h = i - e * H;
    int s, d;
    if (e < E) { s = ei[e]; d = ei[E + e]; } else { s = d = e - E; }
    float v = leaky(sval[s * H + h] + dval[d * H + h]);
    ee[i] = v;
    atomicMax(&mmax[d * H + h], fmap(v));
}

__global__ void edge_expsum(const int* __restrict__ ei, float* __restrict__ ee,
                            const unsigned* __restrict__ mmax, float* __restrict__ den,
                            int E, int Etot, int H)
{
    int i = blockIdx.x * blockDim.x + threadIdx.x;
    if (i >= Etot * H) return;
    int e = i / H, h = i - e * H;
    int d;
    if (e < E) { d = ei[E + e]; } else { d = e - E; }
    float m = funmap(mmax[d * H + h]);
    float ex = __expf(ee[i] - m);
    ee[i] = ex;
    atomicAdd(&den[d * H + h], ex);
}

// one wave per edge; 64 lanes cover the 64 channels of each head
__global__ __launch_bounds__(256) void edge_accum(
    const int* __restrict__ ei, const float* __restrict__ hw,
    const float* __restrict__ ee, const float* __restrict__ den,
    float* __restrict__ gout, int E, int Etot, int H)
{
    int edge = blockIdx.x * 4 + (threadIdx.x >> 6);
    int lane = threadIdx.x & 63;
    if (edge >= Etot) return;
    int s, d;
    if (edge < E) { s = ei[edge]; d = ei[E + edge]; } else { s = d = edge - E; }
    int C = H * 64;
    for (int h = 0; h < H; ++h) {
        float alpha = ee[(size_t)edge * H + h] / (den[d * H + h] + 1e-16f);
        atomicAdd(&gout[(size_t)d * C + h * 64 + lane],
                  hw[(size_t)s * C + h * 64 + lane] * alpha);
    }
}

// ------------------------------------------------- BatchNorm (batch stats)
__global__ void bn_partial(const float* __restrict__ gout, double* __restrict__ sums,
                           int Nn, int C)
{
    int t = threadIdx.x;
    int c = t % C, sub = t / C, nsub = blockDim.x / C;
    int rbase = blockIdx.x * 32;
    double s = 0.0, sq = 0.0;
    for (int r = rbase + sub; r < rbase + 32; r += nsub) {
        float x = gout[(size_t)r * C + c];
        s += x;
        sq += (double)x * x;
    }
    atomicAdd(&sums[c], s);
    atomicAdd(&sums[C + c], sq);
}

__global__ void bn_finalize(const double* __restrict__ sums, float* __restrict__ mu,
                            float* __restrict__ rstd, int Nn, int C)
{
    int c = threadIdx.x;
    if (c >= C) return;
    double m = sums[c] / Nn;
    double v = sums[C + c] / Nn - m * m;
    mu[c] = (float)m;
    rstd[c] = (float)(1.0 / sqrt(v + 1e-5));
}

__global__ void bn_res_act(const float* __restrict__ gout, const float* __restrict__ res,
                           const float* __restrict__ mu, const float* __restrict__ rstd,
                           const float* __restrict__ g, const float* __restrict__ be,
                           float* __restrict__ out, int total, int C)
{
    int i = blockIdx.x * blockDim.x + threadIdx.x;
    if (i >= total) return;
    int c = i & (C - 1);
    float v = (gout[i] - mu[c]) * rstd[c] * g[c] + be[c] + res[i];
    out[i] = leaky(v);
}

__global__ void jk_max(const float* __restrict__ a, const float* __restrict__ b,
                       const float* __restrict__ c, float* __restrict__ z, int total)
{
    int i = blockIdx.x * blockDim.x + threadIdx.x;
    if (i >= total) return;
    z[i] = fmaxf(fmaxf(a[i], b[i]), c[i]);
}

// ------------------------------------------------- full self-attention
// Row-per-thread flash over a key chunk. grid (nchunk, N/256, heads), 256 thr.
// Each thread: one q-row in regs; K/V rows broadcast from LDS (conflict-free).
// Emits per-chunk (m, l, acc[32]) partials; attn_combine merges chunks.
__global__ __launch_bounds__(256) void attn_partial(
    const float* __restrict__ qg, const float* __restrict__ kg,
    const float* __restrict__ vg, float* __restrict__ pm,
    float* __restrict__ pl, float* __restrict__ pacc,
    int N, int nchunk, int chunksz)
{
    __shared__ __align__(16) float klds[128][32];
    __shared__ __align__(16) float vlds[128][32];
    const int head = blockIdx.z;
    const int row = blockIdx.y * 256 + threadIdx.x;
    const int chunk = blockIdx.x;
    const int k0 = chunk * chunksz;
    const float scale = 0.17677669529663687f; // 1/sqrt(32)

    float q[32];
    {
        const float* qp = qg + (size_t)row * 64 + head * 32;
#pragma unroll
        for (int c4 = 0; c4 < 8; ++c4) {
            float4 t = *(const float4*)(qp + c4 * 4);
            q[c4 * 4 + 0] = t.x * scale;
            q[c4 * 4 + 1] = t.y * scale;
            q[c4 * 4 + 2] = t.z * scale;
            q[c4 * 4 + 3] = t.w * scale;
        }
    }
    float acc[32] = {};
    float m = -1e30f, l = 0.f;

    for (int t0 = k0; t0 < k0 + chunksz; t0 += 128) {
        __syncthreads();
        for (int idx = threadIdx.x; idx < 128 * 8; idx += 256) {
            int r = idx >> 3, c4 = idx & 7;
            *(float4*)&klds[r][c4 * 4] =
                *(const float4*)&kg[(size_t)(t0 + r) * 64 + head * 32 + c4 * 4];
            *(float4*)&vlds[r][c4 * 4] =
                *(const float4*)&vg[(size_t)(t0 + r) * 64 + head * 32 + c4 * 4];
        }
        __syncthreads();
        for (int sub = 0; sub < 128; sub += 16) {
            float s[16];
#pragma unroll
            for (int i = 0; i < 16; ++i) {
                float s0 = 0.f, s1 = 0.f, s2 = 0.f, s3 = 0.f;
#pragma unroll
                for (int c4 = 0; c4 < 8; ++c4) {
                    float4 k4 = *(const float4*)&klds[sub + i][c4 * 4];
                    s0 += q[c4 * 4 + 0] * k4.x;
                    s1 += q[c4 * 4 + 1] * k4.y;
                    s2 += q[c4 * 4 + 2] * k4.z;
                    s3 += q[c4 * 4 + 3] * k4.w;
                }
                s[i] = (s0 + s1) + (s2 + s3);
            }
            // branchless sub-tile rescale
            float tm = fmaxf(s[0], s[1]);
#pragma unroll
            for (int i = 2; i < 16; ++i) tm = fmaxf(tm, s[i]);
            float nm = fmaxf(m, tm);
            float corr = __expf(m - nm);
            l *= corr;
#pragma unroll
            for (int c = 0; c < 32; ++c) acc[c] *= corr;
            m = nm;
#pragma unroll
            for (int i = 0; i < 16; ++i) {
                float p = __expf(s[i] - m);
                l += p;
#pragma unroll
                for (int c4 = 0; c4 < 8; ++c4) {
                    float4 v4 = *(const float4*)&vlds[sub + i][c4 * 4];
                    acc[c4 * 4 + 0] += p * v4.x;
                    acc[c4 * 4 + 1] += p * v4.y;
                    acc[c4 * 4 + 2] += p * v4.z;
                    acc[c4 * 4 + 3] += p * v4.w;
                }
            }
        }
    }

    const int hr = head * N + row;
    pm[(size_t)hr * nchunk + chunk] = m;
    pl[(size_t)hr * nchunk + chunk] = l;
    float* ap = pacc + ((size_t)hr * nchunk + chunk) * 32;
#pragma unroll
    for (int c4 = 0; c4 < 8; ++c4) {
        *(float4*)(ap + c4 * 4) =
            make_float4(acc[c4 * 4], acc[c4 * 4 + 1], acc[c4 * 4 + 2], acc[c4 * 4 + 3]);
    }
}

__global__ void attn_combine(const float* __restrict__ pm, const float* __restrict__ pl,
                             const float* __restrict__ pacc, float* __restrict__ og,
                             int N, int nchunk)
{
    int i = blockIdx.x * blockDim.x + threadIdx.x;
    if (i >= 2 * N * 32) return;
    int hr = i >> 5, cc = i & 31;
    float m = -1e30f;
    for (int c = 0; c < nchunk; ++c) m = fmaxf(m, pm[(size_t)hr * nchunk + c]);
    float l = 0.f, a = 0.f;
    for (int c = 0; c < nchunk; ++c) {
        float w = __expf(pm[(size_t)hr * nchunk + c] - m);
        l += pl[(size_t)hr * nchunk + c] * w;
        a += pacc[((size_t)hr * nchunk + c) * 32 + cc] * w;
    }
    int head = hr / N, row = hr - head * N;
    og[(size_t)row * 64 + head * 32 + cc] = a / l;
}

// ----------------------------------------------------------------- host
extern "C" void kernel_launch(void* const* d_in, const int* in_sizes, int n_in,
                              void* d_out, int out_size, void* d_ws, size_t ws_size,
                              hipStream_t stream)
{
    const float* x = (const float*)d_in[0];
    const int* ei = (const int*)d_in[1];
    const float* w[3]  = {(const float*)d_in[2], (const float*)d_in[6],  (const float*)d_in[10]};
    const float* as_[3] = {(const float*)d_in[3], (const float*)d_in[7],  (const float*)d_in[11]};
    const float* ad_[3] = {(const float*)d_in[4], (const float*)d_in[8],  (const float*)d_in[12]};
    const float* rw[3] = {(const float*)d_in[5], (const float*)d_in[9],  (const float*)d_in[13]};
    const float* p0 = (const float*)d_in[14];
    const float* p1 = (const float*)d_in[15];
    const float* qw = (const float*)d_in[16];
    const float* kw = (const float*)d_in[17];
    const float* vw = (const float*)d_in[18];
    const float* ow = (const float*)d_in[19];
    const float* m1w = (const float*)d_in[20];
    const float* m2w = (const float*)d_in[21];
    const float* m3w = (const float*)d_in[22];
    const float* g_[3]  = {(const float*)d_in[23], (const float*)d_in[24], (const float*)d_in[25]};
    const float* be_[3] = {(const float*)d_in[26], (const float*)d_in[27], (const float*)d_in[28]};
    // d_in[29..31] = b0,b1,b2: constant shift cancels exactly inside BatchNorm -> unused
    const float* qb  = (const float*)d_in[32];
    const float* kb  = (const float*)d_in[33];
    const float* vb  = (const float*)d_in[34];
    const float* ob  = (const float*)d_in[35];
    const float* m1b = (const float*)d_in[36];
    const float* m2b = (const float*)d_in[37];
    const float* m3b = (const float*)d_in[38];

    const int N = in_sizes[0] / 64;     // 8192
    const int E = in_sizes[1] / 2;      // 262144
    const int Etot = E + N;             // with self-loops

    float* ws = (float*)d_ws;
    size_t off = 0;
    auto alloc = [&](size_t n) {
        float* p = ws + off;
        off += (n + 255) & ~(size_t)255;
        return p;
    };
    float* hw   = alloc((size_t)N * 256);
    float* res  = alloc((size_t)N * 256);
    float* gout = alloc((size_t)N * 256);
    float* h0   = alloc((size_t)N * 256);
    float* h1   = alloc((size_t)N * 256);
    float* h2   = alloc((size_t)N * 64);
    float* sval = alloc((size_t)N * 4);
    float* dval = alloc((size_t)N * 4);
    float* mmax = alloc((size_t)N * 4);
    float* den  = alloc((size_t)N * 4);
    float* ee   = alloc((size_t)Etot * 4);
    double* bnsum = (double*)alloc(1024);   // 2*256 doubles
    float* mu   = alloc(256);
    float* rstd = alloc(256);
    // aliases for the post-GAT stages (hw/res/gout free by then)
    float* zq = hw;
    float* zk = hw + (size_t)N * 64;
    float* zv = hw + 2 * (size_t)N * 64;
    float* ao = hw + 3 * (size_t)N * 64;
    float* z  = gout;
    float* tA = res;
    float* tB = res + (size_t)N * 64;
    float* tC = res + 2 * (size_t)N * 64;
    // attention partials live in h0..h2 (dead after jk_max):
    // pacc: 2N*8*32 floats (16.8MB), pm/pl: 2N*8 each.
    const int NCHUNK = 8;
    float* pacc = h0;
    float* pm   = h0 + (size_t)2 * N * NCHUNK * 32;
    float* pl   = pm + (size_t)2 * N * NCHUNK;

    auto gemm = [&](const float* A, const float* B, const float* bias, float* C,
                    int M, int Nc, int K, int act) {
        dim3 grid((Nc + 63) / 64, (M + 63) / 64);
        gemm_bias_act<<<grid, 256, 0, stream>>>(A, B, bias, C, M, Nc, K, act);
    };

    const float* hin = x;
    int Kin = 64;
    float* houts[3] = {h0, h1, h2};
    int heads[3] = {4, 4, 1};

    for (int l = 0; l < 3; ++l) {
        int H = heads[l], C = H * 64;
        gemm(hin, w[l], nullptr, hw, N, C, Kin, 0);
        gemm(hin, rw[l], nullptr, res, N, C, Kin, 0);
        sd_kernel<<<(N * H + 255) / 256, 256, 0, stream>>>(hw, as_[l], ad_[l], sval, dval, N, H);
        hipMemsetAsync(mmax, 0, (size_t)N * H * 4, stream);
        hipMemsetAsync(den, 0, (size_t)N * H * 4, stream);
        hipMemsetAsync(gout, 0, (size_t)N * C * 4, stream);
        int tot = Etot * H;
        edge_score<<<(tot + 255) / 256, 256, 0, stream>>>(ei, sval, dval, ee, (unsigned*)mmax, E, Etot, H);
        edge_expsum<<<(tot + 255) / 256, 256, 0, stream>>>(ei, ee, (const unsigned*)mmax, den, E, Etot, H);
        edge_accum<<<(Etot + 3) / 4, 256, 0, stream>>>(ei, hw, ee, den, gout, E, Etot, H);
        hipMemsetAsync(bnsum, 0, (size_t)2 * C * 8, stream);
        bn_partial<<<N / 32, 256, 0, stream>>>(gout, bnsum, N, C);
        bn_finalize<<<1, 256, 0, stream>>>(bnsum, mu, rstd, N, C);
        bn_res_act<<<((size_t)N * C) / 256, 256, 0, stream>>>(gout, res, mu, rstd, g_[l], be_[l], houts[l], N * C, C);
        hin = houts[l];
        Kin = C;
    }

    // JumpingKnowledge max
    gemm(h0, p0, nullptr, tA, N, 64, 256, 0);
    gemm(h1, p1, nullptr, tB, N, 64, 256, 0);
    jk_max<<<((size_t)N * 64) / 256, 256, 0, stream>>>(tA, tB, h2, z, N * 64);

    // self-attention (flash, key-chunked)
    gemm(z, qw, qb, zq, N, 64, 64, 0);
    gemm(z, kw, kb, zk, N, 64, 64, 0);
    gemm(z, vw, vb, zv, N, 64, 64, 0);
    attn_partial<<<dim3(NCHUNK, N / 256, 2), 256, 0, stream>>>(
        zq, zk, zv, pm, pl, pacc, N, NCHUNK, N / NCHUNK);
    attn_combine<<<(2 * N * 32 + 255) / 256, 256, 0, stream>>>(pm, pl, pacc, ao, N, NCHUNK);
    gemm(ao, ow, ob, tA, N, 64, 64, 0);

    // MLP head
    gemm(tA, m1w, m1b, tB, N, 64, 64, 1);
    gemm(tB, m2w, m2b, tC, N, 32, 64, 1);
    gemm(tC, m3w, m3b, (float*)d_out, N, 10, 32, 0);
}

// Round 3
// 966.424 us; speedup vs baseline: 1.7387x; 1.5773x over previous
//
#include <hip/hip_runtime.h>
#include <hip/hip_bf16.h>

// NeuronGAT forward. Round 2:
//  - attn: RQ=2 rows/thread (halves LDS bytes per FLOP), NCHUNK=16, bf16 partials
//  - GAT: CSR build (once) + fused per-node softmax-gather (no float atomics)
//  - GEMM: TK=32 float4-staged 64x64 tiler (N=256) + skinny kernel (N<=64)

#define NEG 0.2f

__device__ __forceinline__ float leaky(float v) { return v > 0.f ? v : NEG * v; }

// ---------------------------------------------------------------- GEMM 64x64
// C[M,N] = act(A[M,K] @ B[K,N] + bias). M%64==0, K%32==0. Used for N=256.
__global__ __launch_bounds__(256) void gemm64(
    const float* __restrict__ A, const float* __restrict__ B,
    const float* __restrict__ bias, float* __restrict__ C,
    int M, int N, int K, int act)
{
    __shared__ __align__(16) float As[32][64];
    __shared__ __align__(16) float Bs[32][64];
    const int tx = threadIdx.x & 15, ty = threadIdx.x >> 4;
    const int row0 = blockIdx.y * 64, col0 = blockIdx.x * 64;
    const int ar = threadIdx.x & 63, akq = threadIdx.x >> 6; // A stage
    const int bc = threadIdx.x & 15, bk = threadIdx.x >> 4;  // B stage
    float acc[4][4] = {};
    for (int k0 = 0; k0 < K; k0 += 32) {
        { // A: 64 rows x 32 k, thread reads 8 contiguous k, writes transposed
            const float* ap = A + (size_t)(row0 + ar) * K + k0 + akq * 8;
            float4 a0 = *(const float4*)ap;
            float4 a1 = *(const float4*)(ap + 4);
            int kb = akq * 8;
            As[kb + 0][ar] = a0.x; As[kb + 1][ar] = a0.y;
            As[kb + 2][ar] = a0.z; As[kb + 3][ar] = a0.w;
            As[kb + 4][ar] = a1.x; As[kb + 5][ar] = a1.y;
            As[kb + 6][ar] = a1.z; As[kb + 7][ar] = a1.w;
        }
#pragma unroll
        for (int j = 0; j < 2; ++j) { // B: 32 k x 64 cols
            int kk = bk + j * 16;
            int col = col0 + bc * 4;
            float4 b;
            if (col + 3 < N) {
                b = *(const float4*)&B[(size_t)(k0 + kk) * N + col];
            } else {
                b.x = col < N ? B[(size_t)(k0 + kk) * N + col] : 0.f;
                b.y = col + 1 < N ? B[(size_t)(k0 + kk) * N + col + 1] : 0.f;
                b.z = col + 2 < N ? B[(size_t)(k0 + kk) * N + col + 2] : 0.f;
                b.w = col + 3 < N ? B[(size_t)(k0 + kk) * N + col + 3] : 0.f;
            }
            *(float4*)&Bs[kk][bc * 4] = b;
        }
        __syncthreads();
#pragma unroll
        for (int kk = 0; kk < 32; ++kk) {
            float4 a4 = *(const float4*)&As[kk][ty * 4];
            float4 b4 = *(const float4*)&Bs[kk][tx * 4];
            float a[4] = {a4.x, a4.y, a4.z, a4.w};
            float b[4] = {b4.x, b4.y, b4.z, b4.w};
#pragma unroll
            for (int i = 0; i < 4; ++i)
#pragma unroll
                for (int j = 0; j < 4; ++j) acc[i][j] += a[i] * b[j];
        }
        __syncthreads();
    }
#pragma unroll
    for (int i = 0; i < 4; ++i) {
        int r = row0 + ty * 4 + i;
#pragma unroll
        for (int j = 0; j < 4; ++j) {
            int c = col0 + tx * 4 + j;
            if (c < N) {
                float v = acc[i][j] + (bias ? bias[c] : 0.f);
                if (act) v = leaky(v);
                C[(size_t)r * N + c] = v;
            }
        }
    }
}

// ------------------------------------------------- GEMM skinny (N <= 64)
// 16 rows x 64 cols per block, 256 threads, acc[4] per thread. M%16==0.
__global__ __launch_bounds__(256) void gemm_skinny(
    const float* __restrict__ A, const float* __restrict__ B,
    const float* __restrict__ bias, float* __restrict__ C,
    int M, int N, int K, int act)
{
    __shared__ __align__(16) float As[16][68];
    __shared__ __align__(16) float Bs[64][64];
    const int rr = threadIdx.x >> 4, c4 = threadIdx.x & 15;
    const int row0 = blockIdx.x * 16;
    float acc[4] = {};
    for (int k0 = 0; k0 < K; k0 += 64) {
        { // A: 16 rows x 64 k; thread (rr as row, c4 as k-quad)
            int k = k0 + c4 * 4;
            float4 a = {0.f, 0.f, 0.f, 0.f};
            const float* ap = &A[(size_t)(row0 + rr) * K + k];
            if (k + 3 < K) a = *(const float4*)ap;
            else {
                if (k < K) a.x = ap[0];
                if (k + 1 < K) a.y = ap[1];
                if (k + 2 < K) a.z = ap[2];
                if (k + 3 < K) a.w = ap[3];
            }
            *(float4*)&As[rr][c4 * 4] = a;
        }
#pragma unroll
        for (int j = 0; j < 4; ++j) { // B: 64 k x N cols (zero-padded)
            int kk = rr + j * 16;
            int col = c4 * 4;
            float4 b = {0.f, 0.f, 0.f, 0.f};
            if (k0 + kk < K) {
                const float* bp = &B[(size_t)(k0 + kk) * N + col];
                if (col + 3 < N) b = *(const float4*)bp;
                else {
                    if (col < N) b.x = bp[0];
                    if (col + 1 < N) b.y = bp[1];
                    if (col + 2 < N) b.z = bp[2];
                    if (col + 3 < N) b.w = bp[3];
                }
            }
            *(float4*)&Bs[kk][col] = b;
        }
        __syncthreads();
#pragma unroll
        for (int kk = 0; kk < 64; ++kk) {
            float a = As[rr][kk];
            float4 b4 = *(const float4*)&Bs[kk][c4 * 4];
            acc[0] += a * b4.x; acc[1] += a * b4.y;
            acc[2] += a * b4.z; acc[3] += a * b4.w;
        }
        __syncthreads();
    }
    int row = row0 + rr, col = c4 * 4;
#pragma unroll
    for (int j = 0; j < 4; ++j) {
        if (col + j < N) {
            float v = acc[j] + (bias ? bias[col + j] : 0.f);
            if (act) v = leaky(v);
            C[(size_t)row * N + col + j] = v;
        }
    }
}

// ------------------------------------------------- GAT attention scores
__global__ void sd_kernel(const float* __restrict__ hw, const float* __restrict__ a_s,
                          const float* __restrict__ a_d, float* __restrict__ sval,
                          float* __restrict__ dval, int Nn, int H)
{
    int i = blockIdx.x * blockDim.x + threadIdx.x;
    if (i >= Nn * H) return;
    int n = i / H, h = i - n * H;
    const float4* row = (const float4*)(hw + (size_t)n * H * 64 + h * 64);
    const float4* as4 = (const float4*)(a_s + h * 64);
    const float4* ad4 = (const float4*)(a_d + h * 64);
    float s = 0.f, d = 0.f;
#pragma unroll
    for (int c = 0; c < 16; ++c) {
        float4 x = row[c], a = as4[c], b = ad4[c];
        s += x.x * a.x + x.y * a.y + x.z * a.z + x.w * a.w;
        d += x.x * b.x + x.y * b.y + x.z * b.z + x.w * b.w;
    }
    sval[i] = s;
    dval[i] = d;
}

// ------------------------------------------------- CSR build (by dst)
__global__ void csr_count(const int* __restrict__ ei, int* __restrict__ cnt, int E) {
    int i = blockIdx.x * 256 + threadIdx.x;
    if (i < E) atomicAdd(&cnt[ei[E + i]], 1);
}

// Nn must equal 256*32 = 8192
__global__ __launch_bounds__(256) void csr_scan(const int* __restrict__ cnt,
                                                int* __restrict__ rowptr,
                                                int* __restrict__ fill, int Nn)
{
    __shared__ int part[256];
    int t = threadIdx.x;
    int loc[32];
    int s = 0;
#pragma unroll
    for (int j = 0; j < 32; ++j) { loc[j] = s; s += cnt[t * 32 + j]; }
    part[t] = s;
    __syncthreads();
    for (int d = 1; d < 256; d <<= 1) {
        int v = (t >= d) ? part[t - d] : 0;
        __syncthreads();
        part[t] += v;
        __syncthreads();
    }
    int off = (t > 0) ? part[t - 1] : 0;
#pragma unroll
    for (int j = 0; j < 32; ++j) {
        int v = off + loc[j];
        rowptr[t * 32 + j] = v;
        fill[t * 32 + j] = v;
    }
    if (t == 255) rowptr[Nn] = part[255];
}

__global__ void csr_scatter(const int* __restrict__ ei, int* __restrict__ fill,
                            int* __restrict__ srcidx, int E) {
    int i = blockIdx.x * 256 + threadIdx.x;
    if (i < E) {
        int d = ei[E + i];
        int p = atomicAdd(&fill[d], 1);
        srcidx[p] = ei[i];
    }
}

// ------------------------------------------------- fused GAT gather
// One wave per dst node. Softmax (incl. self-loop) over in-edges, then
// channel-parallel weighted gather. No atomics, no gout memset needed.
template <int H>
__global__ __launch_bounds__(256) void gat_gather(
    const int* __restrict__ rowptr, const int* __restrict__ srcidx,
    const float* __restrict__ hw, const float* __restrict__ sval,
    const float* __restrict__ dval, float* __restrict__ gout, int Nn)
{
    const int node = blockIdx.x * 4 + (threadIdx.x >> 6);
    const int lane = threadIdx.x & 63;
    const int beg = rowptr[node], end = rowptr[node + 1];
    const int C = H * 64;
    float dv[H], es[H], mh[H], lh[H], inv[H], acc[H];
#pragma unroll
    for (int h = 0; h < H; ++h) {
        dv[h] = dval[node * H + h];
        es[h] = leaky(sval[node * H + h] + dv[h]); // self-loop score
        mh[h] = -1e30f;
        lh[h] = 0.f;
    }
    // pass 1a: max over in-edges (lanes split edges)
    for (int i = beg + lane; i < end; i += 64) {
        int s = srcidx[i];
#pragma unroll
        for (int h = 0; h < H; ++h)
            mh[h] = fmaxf(mh[h], leaky(sval[s * H + h] + dv[h]));
    }
#pragma unroll
    for (int h = 0; h < H; ++h) {
        float m = mh[h];
        for (int off = 32; off; off >>= 1) m = fmaxf(m, __shfl_xor(m, off));
        mh[h] = fmaxf(m, es[h]);
    }
    // pass 1b: sum of exp
    for (int i = beg + lane; i < end; i += 64) {
        int s = srcidx[i];
#pragma unroll
        for (int h = 0; h < H; ++h)
            lh[h] += __expf(leaky(sval[s * H + h] + dv[h]) - mh[h]);
    }
#pragma unroll
    for (int h = 0; h < H; ++h) {
        float l = lh[h];
        for (int off = 32; off; off >>= 1) l += __shfl_xor(l, off);
        l += __expf(es[h] - mh[h]);
        inv[h] = 1.f / (l + 1e-16f);
        acc[h] = __expf(es[h] - mh[h]) * inv[h] *
                 hw[(size_t)node * C + h * 64 + lane];
    }
    // pass 2: channel-parallel gather (lane = channel)
    for (int i = beg; i < end; ++i) {
        int s = srcidx[i];
#pragma unroll
        for (int h = 0; h < H; ++h) {
            float e = leaky(sval[s * H + h] + dv[h]);
            float a = __expf(e - mh[h]) * inv[h];
            acc[h] += a * hw[(size_t)s * C + h * 64 + lane];
        }
    }
#pragma unroll
    for (int h = 0; h < H; ++h)
        gout[(size_t)node * C + h * 64 + lane] = acc[h];
}

// ------------------------------------------------- BatchNorm (batch stats)
__global__ void bn_partial(const float* __restrict__ gout, double* __restrict__ sums,
                           int Nn, int C)
{
    int t = threadIdx.x;
    int c = t % C, sub = t / C, nsub = blockDim.x / C;
    int rbase = blockIdx.x * 32;
    double s = 0.0, sq = 0.0;
    for (int r = rbase + sub; r < rbase + 32; r += nsub) {
        float x = gout[(size_t)r * C + c];
        s += x;
        sq += (double)x * x;
    }
    atomicAdd(&sums[c], s);
    atomicAdd(&sums[C + c], sq);
}

__global__ void bn_finalize(const double* __restrict__ sums, float* __restrict__ mu,
                            float* __restrict__ rstd, int Nn, int C)
{
    int c = threadIdx.x;
    if (c >= C) return;
    double m = sums[c] / Nn;
    double v = sums[C + c] / Nn - m * m;
    mu[c] = (float)m;
    rstd[c] = (float)(1.0 / sqrt(v + 1e-5));
}

__global__ void bn_res_act(const float* __restrict__ gout, const float* __restrict__ res,
                           const float* __restrict__ mu, const float* __restrict__ rstd,
                           const float* __restrict__ g, const float* __restrict__ be,
                           float* __restrict__ out, int total, int C)
{
    int i = blockIdx.x * blockDim.x + threadIdx.x;
    if (i >= total) return;
    int c = i & (C - 1);
    float v = (gout[i] - mu[c]) * rstd[c] * g[c] + be[c] + res[i];
    out[i] = leaky(v);
}

__global__ void jk_max(const float* __restrict__ a, const float* __restrict__ b,
                       const float* __restrict__ c, float* __restrict__ z, int total)
{
    int i = blockIdx.x * blockDim.x + threadIdx.x;
    if (i >= total) return;
    z[i] = fmaxf(fmaxf(a[i], b[i]), c[i]);
}

// ------------------------------------------------- full self-attention
// RQ=2 rows/thread flash over a key chunk; partial acc stored as bf16.
__global__ __launch_bounds__(256) void attn_partial(
    const float* __restrict__ qg, const float* __restrict__ kg,
    const float* __restrict__ vg, float* __restrict__ pm,
    float* __restrict__ pl, __hip_bfloat16* __restrict__ pacc,
    int N, int nchunk, int chunksz)
{
    __shared__ __align__(16) float klds[128][32];
    __shared__ __align__(16) float vlds[128][32];
    const int head = blockIdx.z;
    const int row0 = blockIdx.y * 512 + threadIdx.x; // second row: +256
    const int chunk = blockIdx.x;
    const int kbase = chunk * chunksz;
    const float scale = 0.17677669529663687f; // 1/sqrt(32)

    float q0[32], q1[32];
    {
        const float* qp0 = qg + (size_t)row0 * 64 + head * 32;
        const float* qp1 = qp0 + 256 * 64;
#pragma unroll
        for (int c4 = 0; c4 < 8; ++c4) {
            float4 t0 = *(const float4*)(qp0 + c4 * 4);
            float4 t1 = *(const float4*)(qp1 + c4 * 4);
            q0[c4 * 4 + 0] = t0.x * scale; q0[c4 * 4 + 1] = t0.y * scale;
            q0[c4 * 4 + 2] = t0.z * scale; q0[c4 * 4 + 3] = t0.w * scale;
            q1[c4 * 4 + 0] = t1.x * scale; q1[c4 * 4 + 1] = t1.y * scale;
            q1[c4 * 4 + 2] = t1.z * scale; q1[c4 * 4 + 3] = t1.w * scale;
        }
    }
    float acc0[32] = {}, acc1[32] = {};
    float m0 = -1e30f, m1 = -1e30f, l0 = 0.f, l1 = 0.f;

    for (int t0 = kbase; t0 < kbase + chunksz; t0 += 128) {
        __syncthreads();
        for (int idx = threadIdx.x; idx < 128 * 8; idx += 256) {
            int r = idx >> 3, c4 = idx & 7;
            *(float4*)&klds[r][c4 * 4] =
                *(const float4*)&kg[(size_t)(t0 + r) * 64 + head * 32 + c4 * 4];
            *(float4*)&vlds[r][c4 * 4] =
                *(const float4*)&vg[(size_t)(t0 + r) * 64 + head * 32 + c4 * 4];
        }
        __syncthreads();
        for (int sub = 0; sub < 128; sub += 16) {
            float s0[16], s1[16];
#pragma unroll
            for (int i = 0; i < 16; ++i) {
                float a0 = 0.f, b0 = 0.f, a1 = 0.f, b1 = 0.f;
#pragma unroll
                for (int c4 = 0; c4 < 8; ++c4) {
                    float4 k4 = *(const float4*)&klds[sub + i][c4 * 4];
                    a0 += q0[c4 * 4 + 0] * k4.x + q0[c4 * 4 + 1] * k4.y;
                    b0 += q0[c4 * 4 + 2] * k4.z + q0[c4 * 4 + 3] * k4.w;
                    a1 += q1[c4 * 4 + 0] * k4.x + q1[c4 * 4 + 1] * k4.y;
                    b1 += q1[c4 * 4 + 2] * k4.z + q1[c4 * 4 + 3] * k4.w;
                }
                s0[i] = a0 + b0;
                s1[i] = a1 + b1;
            }
            float tm0 = fmaxf(s0[0], s0[1]), tm1 = fmaxf(s1[0], s1[1]);
#pragma unroll
            for (int i = 2; i < 16; ++i) {
                tm0 = fmaxf(tm0, s0[i]);
                tm1 = fmaxf(tm1, s1[i]);
            }
            float nm0 = fmaxf(m0, tm0), nm1 = fmaxf(m1, tm1);
            float cr0 = __expf(m0 - nm0), cr1 = __expf(m1 - nm1);
            l0 *= cr0; l1 *= cr1;
#pragma unroll
            for (int c = 0; c < 32; ++c) { acc0[c] *= cr0; acc1[c] *= cr1; }
            m0 = nm0; m1 = nm1;
#pragma unroll
            for (int i = 0; i < 16; ++i) {
                float p0 = __expf(s0[i] - m0);
                float p1 = __expf(s1[i] - m1);
                l0 += p0; l1 += p1;
#pragma unroll
                for (int c4 = 0; c4 < 8; ++c4) {
                    float4 v4 = *(const float4*)&vlds[sub + i][c4 * 4];
                    acc0[c4 * 4 + 0] += p0 * v4.x; acc0[c4 * 4 + 1] += p0 * v4.y;
                    acc0[c4 * 4 + 2] += p0 * v4.z; acc0[c4 * 4 + 3] += p0 * v4.w;
                    acc1[c4 * 4 + 0] += p1 * v4.x; acc1[c4 * 4 + 1] += p1 * v4.y;
                    acc1[c4 * 4 + 2] += p1 * v4.z; acc1[c4 * 4 + 3] += p1 * v4.w;
                }
            }
        }
    }
    const size_t hr0 = (size_t)head * N + row0;
    const size_t hr1 = hr0 + 256;
    pm[hr0 * nchunk + chunk] = m0;
    pm[hr1 * nchunk + chunk] = m1;
    pl[hr0 * nchunk + chunk] = l0;
    pl[hr1 * nchunk + chunk] = l1;
    __hip_bfloat16* a0p = pacc + (hr0 * nchunk + chunk) * 32;
    __hip_bfloat16* a1p = pacc + (hr1 * nchunk + chunk) * 32;
#pragma unroll
    for (int c = 0; c < 32; ++c) {
        a0p[c] = __float2bfloat16(acc0[c]);
        a1p[c] = __float2bfloat16(acc1[c]);
    }
}

__global__ void attn_combine(const float* __restrict__ pm, const float* __restrict__ pl,
                             const __hip_bfloat16* __restrict__ pacc,
                             float* __restrict__ og, int N, int nchunk)
{
    int i = blockIdx.x * blockDim.x + threadIdx.x;
    if (i >= 2 * N * 32) return;
    int hr = i >> 5, cc = i & 31;
    float m = -1e30f;
    for (int c = 0; c < nchunk; ++c) m = fmaxf(m, pm[(size_t)hr * nchunk + c]);
    float l = 0.f, a = 0.f;
    for (int c = 0; c < nchunk; ++c) {
        float w = __expf(pm[(size_t)hr * nchunk + c] - m);
        l += pl[(size_t)hr * nchunk + c] * w;
        a += __bfloat162float(pacc[((size_t)hr * nchunk + c) * 32 + cc]) * w;
    }
    int head = hr / N, row = hr - head * N;
    og[(size_t)row * 64 + head * 32 + cc] = a / l;
}

// ----------------------------------------------------------------- host
extern "C" void kernel_launch(void* const* d_in, const int* in_sizes, int n_in,
                              void* d_out, int out_size, void* d_ws, size_t ws_size,
                              hipStream_t stream)
{
    const float* x = (const float*)d_in[0];
    const int* ei = (const int*)d_in[1];
    const float* w[3]   = {(const float*)d_in[2], (const float*)d_in[6],  (const float*)d_in[10]};
    const float* as_[3] = {(const float*)d_in[3], (const float*)d_in[7],  (const float*)d_in[11]};
    const float* ad_[3] = {(const float*)d_in[4], (const float*)d_in[8],  (const float*)d_in[12]};
    const float* rw[3]  = {(const float*)d_in[5], (const float*)d_in[9],  (const float*)d_in[13]};
    const float* p0 = (const float*)d_in[14];
    const float* p1 = (const float*)d_in[15];
    const float* qw = (const float*)d_in[16];
    const float* kw = (const float*)d_in[17];
    const float* vw = (const float*)d_in[18];
    const float* ow = (const float*)d_in[19];
    const float* m1w = (const float*)d_in[20];
    const float* m2w = (const float*)d_in[21];
    const float* m3w = (const float*)d_in[22];
    const float* g_[3]  = {(const float*)d_in[23], (const float*)d_in[24], (const float*)d_in[25]};
    const float* be_[3] = {(const float*)d_in[26], (const float*)d_in[27], (const float*)d_in[28]};
    // d_in[29..31] = b0,b1,b2: constant shift cancels inside BatchNorm -> unused
    const float* qb  = (const float*)d_in[32];
    const float* kb  = (const float*)d_in[33];
    const float* vb  = (const float*)d_in[34];
    const float* ob  = (const float*)d_in[35];
    const float* m1b = (const float*)d_in[36];
    const float* m2b = (const float*)d_in[37];
    const float* m3b = (const float*)d_in[38];

    const int N = in_sizes[0] / 64; // 8192
    const int E = in_sizes[1] / 2;  // 262144

    float* ws = (float*)d_ws;
    size_t off = 0;
    auto alloc = [&](size_t n) {
        float* p = ws + off;
        off += (n + 255) & ~(size_t)255;
        return p;
    };
    float* hw   = alloc((size_t)N * 256);
    float* res  = alloc((size_t)N * 256);
    float* gout = alloc((size_t)N * 256);
    float* h0   = alloc((size_t)N * 256);
    float* h1   = alloc((size_t)N * 256);
    float* h2   = alloc((size_t)N * 64);
    float* sval = alloc((size_t)N * 4);
    float* dval = alloc((size_t)N * 4);
    double* bnsum = (double*)alloc(1024); // 2*256 doubles
    float* mu   = alloc(256);
    float* rstd = alloc(256);
    int* cnt    = (int*)alloc(N);
    int* rowptr = (int*)alloc(N + 256);
    int* fill   = (int*)alloc(N);
    int* srcidx = (int*)alloc(E);
    // post-GAT aliases (hw/res/gout free by then)
    float* zq = hw;
    float* zk = hw + (size_t)N * 64;
    float* zv = hw + 2 * (size_t)N * 64;
    float* ao = hw + 3 * (size_t)N * 64;
    float* z  = gout;
    float* tA = res;
    float* tB = res + (size_t)N * 64;
    float* tC = res + 2 * (size_t)N * 64;
    // attention partials overlay h0..h2 (dead after jk_max):
    // pacc bf16: 2N*16*32 = 8.39M bf16 = h0+h1 exactly; pm/pl in h2.
    const int NCHUNK = 16;
    __hip_bfloat16* pacc = (__hip_bfloat16*)h0;
    float* pm = h2;
    float* pl = h2 + (size_t)2 * N * NCHUNK;

    auto gemm = [&](const float* A, const float* B, const float* bias, float* C,
                    int M, int Nc, int K, int act) {
        if (Nc <= 64) {
            gemm_skinny<<<M / 16, 256, 0, stream>>>(A, B, bias, C, M, Nc, K, act);
        } else {
            dim3 grid((Nc + 63) / 64, M / 64);
            gemm64<<<grid, 256, 0, stream>>>(A, B, bias, C, M, Nc, K, act);
        }
    };

    // CSR build (edge_index constant across layers)
    hipMemsetAsync(cnt, 0, (size_t)N * 4, stream);
    csr_count<<<(E + 255) / 256, 256, 0, stream>>>(ei, cnt, E);
    csr_scan<<<1, 256, 0, stream>>>(cnt, rowptr, fill, N);
    csr_scatter<<<(E + 255) / 256, 256, 0, stream>>>(ei, fill, srcidx, E);

    const float* hin = x;
    int Kin = 64;
    float* houts[3] = {h0, h1, h2};
    int heads[3] = {4, 4, 1};

    for (int l = 0; l < 3; ++l) {
        int H = heads[l], C = H * 64;
        gemm(hin, w[l], nullptr, hw, N, C, Kin, 0);
        gemm(hin, rw[l], nullptr, res, N, C, Kin, 0);
        sd_kernel<<<(N * H + 255) / 256, 256, 0, stream>>>(hw, as_[l], ad_[l], sval, dval, N, H);
        if (H == 4)
            gat_gather<4><<<N / 4, 256, 0, stream>>>(rowptr, srcidx, hw, sval, dval, gout, N);
        else
            gat_gather<1><<<N / 4, 256, 0, stream>>>(rowptr, srcidx, hw, sval, dval, gout, N);
        hipMemsetAsync(bnsum, 0, (size_t)2 * C * 8, stream);
        bn_partial<<<N / 32, 256, 0, stream>>>(gout, bnsum, N, C);
        bn_finalize<<<1, 256, 0, stream>>>(bnsum, mu, rstd, N, C);
        bn_res_act<<<((size_t)N * C) / 256, 256, 0, stream>>>(gout, res, mu, rstd, g_[l], be_[l], houts[l], N * C, C);
        hin = houts[l];
        Kin = C;
    }

    // JumpingKnowledge max
    gemm(h0, p0, nullptr, tA, N, 64, 256, 0);
    gemm(h1, p1, nullptr, tB, N, 64, 256, 0);
    jk_max<<<((size_t)N * 64) / 256, 256, 0, stream>>>(tA, tB, h2, z, N * 64);

    // self-attention (flash, key-chunked, RQ=2)
    gemm(z, qw, qb, zq, N, 64, 64, 0);
    gemm(z, kw, kb, zk, N, 64, 64, 0);
    gemm(z, vw, vb, zv, N, 64, 64, 0);
    attn_partial<<<dim3(NCHUNK, N / 512, 2), 256, 0, stream>>>(
        zq, zk, zv, pm, pl, pacc, N, NCHUNK, N / NCHUNK);
    attn_combine<<<(2 * N * 32 + 255) / 256, 256, 0, stream>>>(pm, pl, pacc, ao, N, NCHUNK);
    gemm(ao, ow, ob, tA, N, 64, 64, 0);

    // MLP head
    gemm(tA, m1w, m1b, tB, N, 64, 64, 1);
    gemm(tB, m2w, m2b, tC, N, 32, 64, 1);
    gemm(tC, m3w, m3b, (float*)d_out, N, 10, 32, 0);
}

// Round 4
// 739.775 us; speedup vs baseline: 2.2714x; 1.3064x over previous
//
#include <hip/hip_runtime.h>
#include <hip/hip_bf16.h>

// NeuronGAT forward. Round 3:
//  - attn: RQ=2 kept, but online-softmax replaced by fixed per-row upper bound
//    (softmax shift-invariance): no s[16] arrays, no rescale, no pm buffer.
//    Kills the 256-VGPR spills seen in round 2 (WRITE_SIZE 57MB -> ~20MB).
//  - rest unchanged from round 2 (CSR gather, gemm64/skinny).

#define NEG 0.2f

__device__ __forceinline__ float leaky(float v) { return v > 0.f ? v : NEG * v; }

// ---------------------------------------------------------------- GEMM 64x64
// C[M,N] = act(A[M,K] @ B[K,N] + bias). M%64==0, K%32==0. Used for N=256.
__global__ __launch_bounds__(256) void gemm64(
    const float* __restrict__ A, const float* __restrict__ B,
    const float* __restrict__ bias, float* __restrict__ C,
    int M, int N, int K, int act)
{
    __shared__ __align__(16) float As[32][64];
    __shared__ __align__(16) float Bs[32][64];
    const int tx = threadIdx.x & 15, ty = threadIdx.x >> 4;
    const int row0 = blockIdx.y * 64, col0 = blockIdx.x * 64;
    const int ar = threadIdx.x & 63, akq = threadIdx.x >> 6; // A stage
    const int bc = threadIdx.x & 15, bk = threadIdx.x >> 4;  // B stage
    float acc[4][4] = {};
    for (int k0 = 0; k0 < K; k0 += 32) {
        { // A: 64 rows x 32 k, thread reads 8 contiguous k, writes transposed
            const float* ap = A + (size_t)(row0 + ar) * K + k0 + akq * 8;
            float4 a0 = *(const float4*)ap;
            float4 a1 = *(const float4*)(ap + 4);
            int kb = akq * 8;
            As[kb + 0][ar] = a0.x; As[kb + 1][ar] = a0.y;
            As[kb + 2][ar] = a0.z; As[kb + 3][ar] = a0.w;
            As[kb + 4][ar] = a1.x; As[kb + 5][ar] = a1.y;
            As[kb + 6][ar] = a1.z; As[kb + 7][ar] = a1.w;
        }
#pragma unroll
        for (int j = 0; j < 2; ++j) { // B: 32 k x 64 cols
            int kk = bk + j * 16;
            int col = col0 + bc * 4;
            float4 b;
            if (col + 3 < N) {
                b = *(const float4*)&B[(size_t)(k0 + kk) * N + col];
            } else {
                b.x = col < N ? B[(size_t)(k0 + kk) * N + col] : 0.f;
                b.y = col + 1 < N ? B[(size_t)(k0 + kk) * N + col + 1] : 0.f;
                b.z = col + 2 < N ? B[(size_t)(k0 + kk) * N + col + 2] : 0.f;
                b.w = col + 3 < N ? B[(size_t)(k0 + kk) * N + col + 3] : 0.f;
            }
            *(float4*)&Bs[kk][bc * 4] = b;
        }
        __syncthreads();
#pragma unroll
        for (int kk = 0; kk < 32; ++kk) {
            float4 a4 = *(const float4*)&As[kk][ty * 4];
            float4 b4 = *(const float4*)&Bs[kk][tx * 4];
            float a[4] = {a4.x, a4.y, a4.z, a4.w};
            float b[4] = {b4.x, b4.y, b4.z, b4.w};
#pragma unroll
            for (int i = 0; i < 4; ++i)
#pragma unroll
                for (int j = 0; j < 4; ++j) acc[i][j] += a[i] * b[j];
        }
        __syncthreads();
    }
#pragma unroll
    for (int i = 0; i < 4; ++i) {
        int r = row0 + ty * 4 + i;
#pragma unroll
        for (int j = 0; j < 4; ++j) {
            int c = col0 + tx * 4 + j;
            if (c < N) {
                float v = acc[i][j] + (bias ? bias[c] : 0.f);
                if (act) v = leaky(v);
                C[(size_t)r * N + c] = v;
            }
        }
    }
}

// ------------------------------------------------- GEMM skinny (N <= 64)
__global__ __launch_bounds__(256) void gemm_skinny(
    const float* __restrict__ A, const float* __restrict__ B,
    const float* __restrict__ bias, float* __restrict__ C,
    int M, int N, int K, int act)
{
    __shared__ __align__(16) float As[16][68];
    __shared__ __align__(16) float Bs[64][64];
    const int rr = threadIdx.x >> 4, c4 = threadIdx.x & 15;
    const int row0 = blockIdx.x * 16;
    float acc[4] = {};
    for (int k0 = 0; k0 < K; k0 += 64) {
        {
            int k = k0 + c4 * 4;
            float4 a = {0.f, 0.f, 0.f, 0.f};
            const float* ap = &A[(size_t)(row0 + rr) * K + k];
            if (k + 3 < K) a = *(const float4*)ap;
            else {
                if (k < K) a.x = ap[0];
                if (k + 1 < K) a.y = ap[1];
                if (k + 2 < K) a.z = ap[2];
                if (k + 3 < K) a.w = ap[3];
            }
            *(float4*)&As[rr][c4 * 4] = a;
        }
#pragma unroll
        for (int j = 0; j < 4; ++j) {
            int kk = rr + j * 16;
            int col = c4 * 4;
            float4 b = {0.f, 0.f, 0.f, 0.f};
            if (k0 + kk < K) {
                const float* bp = &B[(size_t)(k0 + kk) * N + col];
                if (col + 3 < N) b = *(const float4*)bp;
                else {
                    if (col < N) b.x = bp[0];
                    if (col + 1 < N) b.y = bp[1];
                    if (col + 2 < N) b.z = bp[2];
                    if (col + 3 < N) b.w = bp[3];
                }
            }
            *(float4*)&Bs[kk][col] = b;
        }
        __syncthreads();
#pragma unroll
        for (int kk = 0; kk < 64; ++kk) {
            float a = As[rr][kk];
            float4 b4 = *(const float4*)&Bs[kk][c4 * 4];
            acc[0] += a * b4.x; acc[1] += a * b4.y;
            acc[2] += a * b4.z; acc[3] += a * b4.w;
        }
        __syncthreads();
    }
    int row = row0 + rr, col = c4 * 4;
#pragma unroll
    for (int j = 0; j < 4; ++j) {
        if (col + j < N) {
            float v = acc[j] + (bias ? bias[col + j] : 0.f);
            if (act) v = leaky(v);
            C[(size_t)row * N + col + j] = v;
        }
    }
}

// ------------------------------------------------- GAT attention scores
__global__ void sd_kernel(const float* __restrict__ hw, const float* __restrict__ a_s,
                          const float* __restrict__ a_d, float* __restrict__ sval,
                          float* __restrict__ dval, int Nn, int H)
{
    int i = blockIdx.x * blockDim.x + threadIdx.x;
    if (i >= Nn * H) return;
    int n = i / H, h = i - n * H;
    const float4* row = (const float4*)(hw + (size_t)n * H * 64 + h * 64);
    const float4* as4 = (const float4*)(a_s + h * 64);
    const float4* ad4 = (const float4*)(a_d + h * 64);
    float s = 0.f, d = 0.f;
#pragma unroll
    for (int c = 0; c < 16; ++c) {
        float4 x = row[c], a = as4[c], b = ad4[c];
        s += x.x * a.x + x.y * a.y + x.z * a.z + x.w * a.w;
        d += x.x * b.x + x.y * b.y + x.z * b.z + x.w * b.w;
    }
    sval[i] = s;
    dval[i] = d;
}

// ------------------------------------------------- CSR build (by dst)
__global__ void csr_count(const int* __restrict__ ei, int* __restrict__ cnt, int E) {
    int i = blockIdx.x * 256 + threadIdx.x;
    if (i < E) atomicAdd(&cnt[ei[E + i]], 1);
}

__global__ __launch_bounds__(256) void csr_scan(const int* __restrict__ cnt,
                                                int* __restrict__ rowptr,
                                                int* __restrict__ fill, int Nn)
{
    __shared__ int part[256];
    int t = threadIdx.x;
    int loc[32];
    int s = 0;
#pragma unroll
    for (int j = 0; j < 32; ++j) { loc[j] = s; s += cnt[t * 32 + j]; }
    part[t] = s;
    __syncthreads();
    for (int d = 1; d < 256; d <<= 1) {
        int v = (t >= d) ? part[t - d] : 0;
        __syncthreads();
        part[t] += v;
        __syncthreads();
    }
    int off = (t > 0) ? part[t - 1] : 0;
#pragma unroll
    for (int j = 0; j < 32; ++j) {
        int v = off + loc[j];
        rowptr[t * 32 + j] = v;
        fill[t * 32 + j] = v;
    }
    if (t == 255) rowptr[Nn] = part[255];
}

__global__ void csr_scatter(const int* __restrict__ ei, int* __restrict__ fill,
                            int* __restrict__ srcidx, int E) {
    int i = blockIdx.x * 256 + threadIdx.x;
    if (i < E) {
        int d = ei[E + i];
        int p = atomicAdd(&fill[d], 1);
        srcidx[p] = ei[i];
    }
}

// ------------------------------------------------- fused GAT gather
template <int H>
__global__ __launch_bounds__(256) void gat_gather(
    const int* __restrict__ rowptr, const int* __restrict__ srcidx,
    const float* __restrict__ hw, const float* __restrict__ sval,
    const float* __restrict__ dval, float* __restrict__ gout, int Nn)
{
    const int node = blockIdx.x * 4 + (threadIdx.x >> 6);
    const int lane = threadIdx.x & 63;
    const int beg = rowptr[node], end = rowptr[node + 1];
    const int C = H * 64;
    float dv[H], es[H], mh[H], lh[H], inv[H], acc[H];
#pragma unroll
    for (int h = 0; h < H; ++h) {
        dv[h] = dval[node * H + h];
        es[h] = leaky(sval[node * H + h] + dv[h]); // self-loop score
        mh[h] = -1e30f;
        lh[h] = 0.f;
    }
    for (int i = beg + lane; i < end; i += 64) {
        int s = srcidx[i];
#pragma unroll
        for (int h = 0; h < H; ++h)
            mh[h] = fmaxf(mh[h], leaky(sval[s * H + h] + dv[h]));
    }
#pragma unroll
    for (int h = 0; h < H; ++h) {
        float m = mh[h];
        for (int off = 32; off; off >>= 1) m = fmaxf(m, __shfl_xor(m, off));
        mh[h] = fmaxf(m, es[h]);
    }
    for (int i = beg + lane; i < end; i += 64) {
        int s = srcidx[i];
#pragma unroll
        for (int h = 0; h < H; ++h)
            lh[h] += __expf(leaky(sval[s * H + h] + dv[h]) - mh[h]);
    }
#pragma unroll
    for (int h = 0; h < H; ++h) {
        float l = lh[h];
        for (int off = 32; off; off >>= 1) l += __shfl_xor(l, off);
        l += __expf(es[h] - mh[h]);
        inv[h] = 1.f / (l + 1e-16f);
        acc[h] = __expf(es[h] - mh[h]) * inv[h] *
                 hw[(size_t)node * C + h * 64 + lane];
    }
    for (int i = beg; i < end; ++i) {
        int s = srcidx[i];
#pragma unroll
        for (int h = 0; h < H; ++h) {
            float e = leaky(sval[s * H + h] + dv[h]);
            float a = __expf(e - mh[h]) * inv[h];
            acc[h] += a * hw[(size_t)s * C + h * 64 + lane];
        }
    }
#pragma unroll
    for (int h = 0; h < H; ++h)
        gout[(size_t)node * C + h * 64 + lane] = acc[h];
}

// ------------------------------------------------- BatchNorm (batch stats)
__global__ void bn_partial(const float* __restrict__ gout, double* __restrict__ sums,
                           int Nn, int C)
{
    int t = threadIdx.x;
    int c = t % C, sub = t / C, nsub = blockDim.x / C;
    int rbase = blockIdx.x * 32;
    double s = 0.0, sq = 0.0;
    for (int r = rbase + sub; r < rbase + 32; r += nsub) {
        float x = gout[(size_t)r * C + c];
        s += x;
        sq += (double)x * x;
    }
    atomicAdd(&sums[c], s);
    atomicAdd(&sums[C + c], sq);
}

__global__ void bn_finalize(const double* __restrict__ sums, float* __restrict__ mu,
                            float* __restrict__ rstd, int Nn, int C)
{
    int c = threadIdx.x;
    if (c >= C) return;
    double m = sums[c] / Nn;
    double v = sums[C + c] / Nn - m * m;
    mu[c] = (float)m;
    rstd[c] = (float)(1.0 / sqrt(v + 1e-5));
}

__global__ void bn_res_act(const float* __restrict__ gout, const float* __restrict__ res,
                           const float* __restrict__ mu, const float* __restrict__ rstd,
                           const float* __restrict__ g, const float* __restrict__ be,
                           float* __restrict__ out, int total, int C)
{
    int i = blockIdx.x * blockDim.x + threadIdx.x;
    if (i >= total) return;
    int c = i & (C - 1);
    float v = (gout[i] - mu[c]) * rstd[c] * g[c] + be[c] + res[i];
    out[i] = leaky(v);
}

__global__ void jk_max(const float* __restrict__ a, const float* __restrict__ b,
                       const float* __restrict__ c, float* __restrict__ z, int total)
{
    int i = blockIdx.x * blockDim.x + threadIdx.x;
    if (i >= total) return;
    z[i] = fmaxf(fmaxf(a[i], b[i]), c[i]);
}

// ------------------------------------------------- per-dim |k| max (both heads)
// kmax[c] = max_n |kg[n][c]|, c in [0,64). Non-negative floats -> uint atomicMax.
__global__ void kmax_kernel(const float* __restrict__ kg, unsigned* __restrict__ kmax,
                            int N)
{
    const int c = threadIdx.x & 63, g = threadIdx.x >> 6;
    const int rows = N / (gridDim.x * 4);
    const int r0 = (blockIdx.x * 4 + g) * rows;
    float m = 0.f;
    for (int r = r0; r < r0 + rows; ++r)
        m = fmaxf(m, fabsf(kg[(size_t)r * 64 + c]));
    atomicMax(&kmax[c], __float_as_uint(m));
}

// ------------------------------------------------- full self-attention
// RQ=2 flash over a key chunk with FIXED per-row softmax shift:
// bound = sum_c |scale*q_c| * kmax_c >= any score (Cauchy-Schwarz per dim).
// Softmax is shift-invariant, so no online max/rescale needed; p<=1 always.
__global__ __launch_bounds__(256) void attn_partial(
    const float* __restrict__ qg, const float* __restrict__ kg,
    const float* __restrict__ vg, const unsigned* __restrict__ kmaxu,
    float* __restrict__ pl, __hip_bfloat16* __restrict__ pacc,
    int N, int nchunk, int chunksz)
{
    __shared__ __align__(16) float klds[128][32];
    __shared__ __align__(16) float vlds[128][32];
    const int head = blockIdx.z;
    const int row0 = blockIdx.y * 512 + threadIdx.x; // second row: +256
    const int chunk = blockIdx.x;
    const int kbase = chunk * chunksz;
    const float scale = 0.17677669529663687f; // 1/sqrt(32)

    float q0[32], q1[32];
    {
        const float* qp0 = qg + (size_t)row0 * 64 + head * 32;
        const float* qp1 = qp0 + 256 * 64;
#pragma unroll
        for (int c4 = 0; c4 < 8; ++c4) {
            float4 t0 = *(const float4*)(qp0 + c4 * 4);
            float4 t1 = *(const float4*)(qp1 + c4 * 4);
            q0[c4 * 4 + 0] = t0.x * scale; q0[c4 * 4 + 1] = t0.y * scale;
            q0[c4 * 4 + 2] = t0.z * scale; q0[c4 * 4 + 3] = t0.w * scale;
            q1[c4 * 4 + 0] = t1.x * scale; q1[c4 * 4 + 1] = t1.y * scale;
            q1[c4 * 4 + 2] = t1.z * scale; q1[c4 * 4 + 3] = t1.w * scale;
        }
    }
    float bound0 = 0.f, bound1 = 0.f;
#pragma unroll
    for (int c = 0; c < 32; ++c) {
        float km = __uint_as_float(kmaxu[head * 32 + c]);
        bound0 += fabsf(q0[c]) * km;
        bound1 += fabsf(q1[c]) * km;
    }
    float acc0[32] = {}, acc1[32] = {};
    float l0 = 0.f, l1 = 0.f;

    for (int t0 = kbase; t0 < kbase + chunksz; t0 += 128) {
        __syncthreads();
        for (int idx = threadIdx.x; idx < 128 * 8; idx += 256) {
            int r = idx >> 3, c4 = idx & 7;
            *(float4*)&klds[r][c4 * 4] =
                *(const float4*)&kg[(size_t)(t0 + r) * 64 + head * 32 + c4 * 4];
            *(float4*)&vlds[r][c4 * 4] =
                *(const float4*)&vg[(size_t)(t0 + r) * 64 + head * 32 + c4 * 4];
        }
        __syncthreads();
        for (int kk = 0; kk < 128; kk += 4) {
            float s0[4], s1[4];
#pragma unroll
            for (int i = 0; i < 4; ++i) {
                float a0 = 0.f, b0 = 0.f, a1 = 0.f, b1 = 0.f;
#pragma unroll
                for (int c4 = 0; c4 < 8; ++c4) {
                    float4 k4 = *(const float4*)&klds[kk + i][c4 * 4];
                    a0 += q0[c4 * 4 + 0] * k4.x + q0[c4 * 4 + 1] * k4.y;
                    b0 += q0[c4 * 4 + 2] * k4.z + q0[c4 * 4 + 3] * k4.w;
                    a1 += q1[c4 * 4 + 0] * k4.x + q1[c4 * 4 + 1] * k4.y;
                    b1 += q1[c4 * 4 + 2] * k4.z + q1[c4 * 4 + 3] * k4.w;
                }
                s0[i] = a0 + b0;
                s1[i] = a1 + b1;
            }
            float p0[4], p1[4];
#pragma unroll
            for (int i = 0; i < 4; ++i) {
                p0[i] = __expf(s0[i] - bound0);
                p1[i] = __expf(s1[i] - bound1);
            }
            l0 += (p0[0] + p0[1]) + (p0[2] + p0[3]);
            l1 += (p1[0] + p1[1]) + (p1[2] + p1[3]);
#pragma unroll
            for (int i = 0; i < 4; ++i) {
#pragma unroll
                for (int c4 = 0; c4 < 8; ++c4) {
                    float4 v4 = *(const float4*)&vlds[kk + i][c4 * 4];
                    acc0[c4 * 4 + 0] += p0[i] * v4.x; acc0[c4 * 4 + 1] += p0[i] * v4.y;
                    acc0[c4 * 4 + 2] += p0[i] * v4.z; acc0[c4 * 4 + 3] += p0[i] * v4.w;
                    acc1[c4 * 4 + 0] += p1[i] * v4.x; acc1[c4 * 4 + 1] += p1[i] * v4.y;
                    acc1[c4 * 4 + 2] += p1[i] * v4.z; acc1[c4 * 4 + 3] += p1[i] * v4.w;
                }
            }
        }
    }
    const size_t hr0 = (size_t)head * N + row0;
    const size_t hr1 = hr0 + 256;
    pl[hr0 * nchunk + chunk] = l0;
    pl[hr1 * nchunk + chunk] = l1;
    __hip_bfloat16* a0p = pacc + (hr0 * nchunk + chunk) * 32;
    __hip_bfloat16* a1p = pacc + (hr1 * nchunk + chunk) * 32;
#pragma unroll
    for (int c = 0; c < 32; ++c) {
        a0p[c] = __float2bfloat16(acc0[c]);
        a1p[c] = __float2bfloat16(acc1[c]);
    }
}

// all chunks of a row share the same shift -> plain sums, no max merge
__global__ void attn_combine(const float* __restrict__ pl,
                             const __hip_bfloat16* __restrict__ pacc,
                             float* __restrict__ og, int N, int nchunk)
{
    int i = blockIdx.x * blockDim.x + threadIdx.x;
    if (i >= 2 * N * 32) return;
    int hr = i >> 5, cc = i & 31;
    float l = 0.f, a = 0.f;
    for (int c = 0; c < nchunk; ++c) {
        l += pl[(size_t)hr * nchunk + c];
        a += __bfloat162float(pacc[((size_t)hr * nchunk + c) * 32 + cc]);
    }
    int head = hr / N, row = hr - head * N;
    og[(size_t)row * 64 + head * 32 + cc] = a / l;
}

// ----------------------------------------------------------------- host
extern "C" void kernel_launch(void* const* d_in, const int* in_sizes, int n_in,
                              void* d_out, int out_size, void* d_ws, size_t ws_size,
                              hipStream_t stream)
{
    const float* x = (const float*)d_in[0];
    const int* ei = (const int*)d_in[1];
    const float* w[3]   = {(const float*)d_in[2], (const float*)d_in[6],  (const float*)d_in[10]};
    const float* as_[3] = {(const float*)d_in[3], (const float*)d_in[7],  (const float*)d_in[11]};
    const float* ad_[3] = {(const float*)d_in[4], (const float*)d_in[8],  (const float*)d_in[12]};
    const float* rw[3]  = {(const float*)d_in[5], (const float*)d_in[9],  (const float*)d_in[13]};
    const float* p0 = (const float*)d_in[14];
    const float* p1 = (const float*)d_in[15];
    const float* qw = (const float*)d_in[16];
    const float* kw = (const float*)d_in[17];
    const float* vw = (const float*)d_in[18];
    const float* ow = (const float*)d_in[19];
    const float* m1w = (const float*)d_in[20];
    const float* m2w = (const float*)d_in[21];
    const float* m3w = (const float*)d_in[22];
    const float* g_[3]  = {(const float*)d_in[23], (const float*)d_in[24], (const float*)d_in[25]};
    const float* be_[3] = {(const float*)d_in[26], (const float*)d_in[27], (const float*)d_in[28]};
    // d_in[29..31] = b0,b1,b2: constant shift cancels inside BatchNorm -> unused
    const float* qb  = (const float*)d_in[32];
    const float* kb  = (const float*)d_in[33];
    const float* vb  = (const float*)d_in[34];
    const float* ob  = (const float*)d_in[35];
    const float* m1b = (const float*)d_in[36];
    const float* m2b = (const float*)d_in[37];
    const float* m3b = (const float*)d_in[38];

    const int N = in_sizes[0] / 64; // 8192
    const int E = in_sizes[1] / 2;  // 262144

    float* ws = (float*)d_ws;
    size_t off = 0;
    auto alloc = [&](size_t n) {
        float* p = ws + off;
        off += (n + 255) & ~(size_t)255;
        return p;
    };
    float* hw   = alloc((size_t)N * 256);
    float* res  = alloc((size_t)N * 256);
    float* gout = alloc((size_t)N * 256);
    float* h0   = alloc((size_t)N * 256);
    float* h1   = alloc((size_t)N * 256);
    float* h2   = alloc((size_t)N * 64);
    float* sval = alloc((size_t)N * 4);
    float* dval = alloc((size_t)N * 4);
    double* bnsum = (double*)alloc(1024); // 2*256 doubles
    float* mu   = alloc(256);
    float* rstd = alloc(256);
    int* cnt    = (int*)alloc(N);
    int* rowptr = (int*)alloc(N + 256);
    int* fill   = (int*)alloc(N);
    int* srcidx = (int*)alloc(E);
    unsigned* kmaxu = (unsigned*)alloc(64);
    // post-GAT aliases (hw/res/gout free by then)
    float* zq = hw;
    float* zk = hw + (size_t)N * 64;
    float* zv = hw + 2 * (size_t)N * 64;
    float* ao = hw + 3 * (size_t)N * 64;
    float* z  = gout;
    float* tA = res;
    float* tB = res + (size_t)N * 64;
    float* tC = res + 2 * (size_t)N * 64;
    // attention partials overlay h0..h2 (dead after jk_max):
    // pacc bf16: 2N*16*32 = 8.39M elems (16.8MB) = h0+h1; pl in h2.
    const int NCHUNK = 16;
    __hip_bfloat16* pacc = (__hip_bfloat16*)h0;
    float* pl = h2;

    auto gemm = [&](const float* A, const float* B, const float* bias, float* C,
                    int M, int Nc, int K, int act) {
        if (Nc <= 64) {
            gemm_skinny<<<M / 16, 256, 0, stream>>>(A, B, bias, C, M, Nc, K, act);
        } else {
            dim3 grid((Nc + 63) / 64, M / 64);
            gemm64<<<grid, 256, 0, stream>>>(A, B, bias, C, M, Nc, K, act);
        }
    };

    // CSR build (edge_index constant across layers)
    hipMemsetAsync(cnt, 0, (size_t)N * 4, stream);
    csr_count<<<(E + 255) / 256, 256, 0, stream>>>(ei, cnt, E);
    csr_scan<<<1, 256, 0, stream>>>(cnt, rowptr, fill, N);
    csr_scatter<<<(E + 255) / 256, 256, 0, stream>>>(ei, fill, srcidx, E);

    const float* hin = x;
    int Kin = 64;
    float* houts[3] = {h0, h1, h2};
    int heads[3] = {4, 4, 1};

    for (int l = 0; l < 3; ++l) {
        int H = heads[l], C = H * 64;
        gemm(hin, w[l], nullptr, hw, N, C, Kin, 0);
        gemm(hin, rw[l], nullptr, res, N, C, Kin, 0);
        sd_kernel<<<(N * H + 255) / 256, 256, 0, stream>>>(hw, as_[l], ad_[l], sval, dval, N, H);
        if (H == 4)
            gat_gather<4><<<N / 4, 256, 0, stream>>>(rowptr, srcidx, hw, sval, dval, gout, N);
        else
            gat_gather<1><<<N / 4, 256, 0, stream>>>(rowptr, srcidx, hw, sval, dval, gout, N);
        hipMemsetAsync(bnsum, 0, (size_t)2 * C * 8, stream);
        bn_partial<<<N / 32, 256, 0, stream>>>(gout, bnsum, N, C);
        bn_finalize<<<1, 256, 0, stream>>>(bnsum, mu, rstd, N, C);
        bn_res_act<<<((size_t)N * C) / 256, 256, 0, stream>>>(gout, res, mu, rstd, g_[l], be_[l], houts[l], N * C, C);
        hin = houts[l];
        Kin = C;
    }

    // JumpingKnowledge max
    gemm(h0, p0, nullptr, tA, N, 64, 256, 0);
    gemm(h1, p1, nullptr, tB, N, 64, 256, 0);
    jk_max<<<((size_t)N * 64) / 256, 256, 0, stream>>>(tA, tB, h2, z, N * 64);

    // self-attention (flash, key-chunked, RQ=2, fixed-shift softmax)
    gemm(z, qw, qb, zq, N, 64, 64, 0);
    gemm(z, kw, kb, zk, N, 64, 64, 0);
    gemm(z, vw, vb, zv, N, 64, 64, 0);
    hipMemsetAsync(kmaxu, 0, 64 * 4, stream);
    kmax_kernel<<<32, 256, 0, stream>>>(zk, kmaxu, N);
    attn_partial<<<dim3(NCHUNK, N / 512, 2), 256, 0, stream>>>(
        zq, zk, zv, kmaxu, pl, pacc, N, NCHUNK, N / NCHUNK);
    attn_combine<<<(2 * N * 32 + 255) / 256, 256, 0, stream>>>(pl, pacc, ao, N, NCHUNK);
    gemm(ao, ow, ob, tA, N, 64, 64, 0);

    // MLP head
    gemm(tA, m1w, m1b, tB, N, 64, 64, 1);
    gemm(tB, m2w, m2b, tC, N, 32, 64, 1);
    gemm(tC, m3w, m3b, (float*)d_out, N, 10, 32, 0);
}